// Round 1
// baseline (153.799 us; speedup 1.0000x reference)
//
#include <hip/hip_runtime.h>
#include <math.h>

#define DIM 64
#define HEADS 4
#define BB 8
#define QQ 128
#define VV 128
#define NN (BB*QQ)   // 1024

// K1: Av[h][b][v][j] = sum_i values[b,v,i] * U_{re,im}[h, 64+i, j]
__global__ __launch_bounds__(256) void k_av(const float* __restrict__ values,
                                            const float* __restrict__ U_re,
                                            const float* __restrict__ U_im,
                                            float* __restrict__ Av_re,
                                            float* __restrict__ Av_im) {
    int tid = blockIdx.x * blockDim.x + threadIdx.x;
    int w = tid >> 6;          // wave id: 0..4095  (h, b*128+v)
    int j = tid & 63;
    int h = w >> 10;           // 0..3
    int rem = w & 1023;        // b*128 + v
    const float* vrow = values + rem * DIM;
    float vself = vrow[j];
    const float* ur = U_re + (h * 2 * DIM + DIM) * DIM + j;   // bottom half of U
    const float* ui = U_im + (h * 2 * DIM + DIM) * DIM + j;
    float ar = 0.f, ai = 0.f;
    #pragma unroll 8
    for (int i = 0; i < DIM; ++i) {
        float vi = __shfl(vself, i, 64);
        ar = fmaf(vi, ur[i * DIM], ar);
        ai = fmaf(vi, ui[i * DIM], ai);
    }
    int out = (h * 1024 + rem) * DIM + j;
    Av_re[out] = ar;
    Av_im[out] = ai;
}

// K2: one wave per (h, n). Lane j = state dim. 128-step EUNN scan.
__global__ __launch_bounds__(256) void k_rnn(const float* __restrict__ queries,
                                             const float* __restrict__ U_re,
                                             const float* __restrict__ U_im,
                                             const float* __restrict__ bias,
                                             const float* __restrict__ theta1,
                                             const float* __restrict__ phi1,
                                             const float* __restrict__ theta2,
                                             const float* __restrict__ phi2,
                                             const float* __restrict__ omega,
                                             const float* __restrict__ Av_re,
                                             const float* __restrict__ Av_im,
                                             float* __restrict__ acc) {
    int tid = blockIdx.x * blockDim.x + threadIdx.x;
    int w = tid >> 6;          // 0..4095
    int j = tid & 63;
    int h = w >> 10;           // 0..3
    int n = w & 1023;          // 0..1023
    int b = n >> 7;            // 0..7

    // ---- layer-1 coefficients: out = A1*self + B1*partner(xor 1) ----
    int k1 = j >> 1;
    float th1 = theta1[h * 32 + k1], ph1 = phi1[h * 32 + k1];
    float c1 = cosf(th1), s1 = sinf(th1);
    float A1r, A1i, B1r, B1i;
    if ((j & 1) == 0) {        // 'a' position: e1*(c1*a - s1*b)
        float er = cosf(ph1), ei = sinf(ph1);
        A1r = er * c1; A1i = ei * c1;
        B1r = -er * s1; B1i = -ei * s1;
    } else {                   // 'b' position: s1*a + c1*b
        A1r = c1; A1i = 0.f;
        B1r = s1; B1i = 0.f;
    }

    // ---- layer-2 coefficients (+omega folded): out = A2*self + B2*partner ----
    float A2r, A2i, B2r, B2i;
    int p2lane;
    if (j == 0 || j == 63) {   // endpoints pass through (then phase)
        A2r = 1.f; A2i = 0.f; B2r = 0.f; B2i = 0.f; p2lane = j;
    } else {
        int k2 = (j - 1) >> 1;
        float th2 = theta2[h * 31 + k2], ph2 = phi2[h * 31 + k2];
        float c2 = cosf(th2), s2 = sinf(th2);
        if (j & 1) {           // 'a' position (odd index): e2*(c2*a - s2*b)
            float er = cosf(ph2), ei = sinf(ph2);
            A2r = er * c2; A2i = ei * c2;
            B2r = -er * s2; B2i = -ei * s2;
            p2lane = j + 1;
        } else {               // 'b' position (even index): s2*a + c2*b
            A2r = c2; A2i = 0.f;
            B2r = s2; B2i = 0.f;
            p2lane = j - 1;
        }
    }
    // fold exp(i*omega) into layer-2 coefficients
    {
        float om = omega[h * 64 + j];
        float eor = cosf(om), eoi = sinf(om);
        float tr, ti;
        tr = A2r * eor - A2i * eoi; ti = A2r * eoi + A2i * eor; A2r = tr; A2i = ti;
        tr = B2r * eor - B2i * eoi; ti = B2r * eoi + B2i * eor; B2r = tr; B2i = ti;
    }

    float bj = bias[h * 64 + j];

    // ---- Aq[h,n,j] = sum_i q[n,i] * U_top[h,i,j] (constant input term) ----
    float qself = queries[n * DIM + j];
    const float* ur = U_re + (h * 2 * DIM) * DIM + j;   // top half of U
    const float* ui = U_im + (h * 2 * DIM) * DIM + j;
    float uqr = 0.f, uqi = 0.f;
    #pragma unroll 8
    for (int i = 0; i < DIM; ++i) {
        float qi = __shfl(qself, i, 64);
        uqr = fmaf(qi, ur[i * DIM], uqr);
        uqi = fmaf(qi, ui[i * DIM], uqi);
    }

    const float* avr_p = Av_re + (h * 8 + b) * VV * DIM + j;
    const float* avi_p = Av_im + (h * 8 + b) * VV * DIM + j;

    float hr = 0.f, hi = 0.f;
    #pragma unroll 4
    for (int v = 0; v < VV; ++v) {
        float avr = avr_p[v * DIM];
        float avi = avi_p[v * DIM];
        // layer 1
        float pr = __shfl_xor(hr, 1, 64);
        float pi = __shfl_xor(hi, 1, 64);
        float t_r = A1r * hr - A1i * hi + B1r * pr - B1i * pi;
        float t_i = A1r * hi + A1i * hr + B1r * pi + B1i * pr;
        // layer 2 (+ omega phase)
        float qr = __shfl(t_r, p2lane, 64);
        float qi2 = __shfl(t_i, p2lane, 64);
        float s_r = A2r * t_r - A2i * t_i + B2r * qr - B2i * qi2;
        float s_i = A2r * t_i + A2i * t_r + B2r * qi2 + B2i * qr;
        // add input u = Aq + Av[v]
        float zr = s_r + uqr + avr;
        float zi = s_i + uqi + avi;
        // modrelu: z * relu(|z| + b) / (|z| + 1e-5)
        float m = sqrtf(zr * zr + zi * zi);
        float sc = fmaxf(m + bj, 0.f) / (m + 1e-5f);
        hr = zr * sc;
        hi = zi * sc;
    }
    // acc[n, h*64 + j] = Re(hT)
    acc[n * (HEADS * DIM) + h * DIM + j] = hr;
}

// K3: y[n,j] = b_dense[j] + sum_k acc[n,k] * W[k,j]
__global__ __launch_bounds__(256) void k_dense(const float* __restrict__ acc,
                                               const float* __restrict__ W,
                                               const float* __restrict__ bd,
                                               float* __restrict__ y) {
    int tid = blockIdx.x * blockDim.x + threadIdx.x;  // n*64 + j
    int n = tid >> 6;
    int j = tid & 63;
    const float* arow = acc + n * (HEADS * DIM);
    float s = bd[j];
    #pragma unroll 8
    for (int k = 0; k < HEADS * DIM; ++k) {
        s = fmaf(arow[k], W[k * DIM + j], s);
    }
    y[tid] = s;
}

extern "C" void kernel_launch(void* const* d_in, const int* in_sizes, int n_in,
                              void* d_out, int out_size, void* d_ws, size_t ws_size,
                              hipStream_t stream) {
    const float* queries = (const float*)d_in[0];
    const float* values  = (const float*)d_in[1];
    const float* U_re    = (const float*)d_in[2];
    const float* U_im    = (const float*)d_in[3];
    const float* bias    = (const float*)d_in[4];
    const float* theta1  = (const float*)d_in[5];
    const float* phi1    = (const float*)d_in[6];
    const float* theta2  = (const float*)d_in[7];
    const float* phi2    = (const float*)d_in[8];
    const float* omega   = (const float*)d_in[9];
    const float* W_dense = (const float*)d_in[10];
    const float* b_dense = (const float*)d_in[11];
    float* y = (float*)d_out;

    const int AV_ELEMS = HEADS * BB * VV * DIM;   // 262144
    float* Av_re = (float*)d_ws;
    float* Av_im = Av_re + AV_ELEMS;
    float* acc   = Av_im + AV_ELEMS;              // 1024 x 256

    // K1: 4096 waves (h,b,v), 4 waves/block
    k_av<<<1024, 256, 0, stream>>>(values, U_re, U_im, Av_re, Av_im);
    // K2: 4096 waves (h,n), 4 waves/block
    k_rnn<<<1024, 256, 0, stream>>>(queries, U_re, U_im, bias, theta1, phi1,
                                    theta2, phi2, omega, Av_re, Av_im, acc);
    // K3: 65536 threads
    k_dense<<<256, 256, 0, stream>>>(acc, W_dense, b_dense, y);
}

// Round 2
// 126.362 us; speedup vs baseline: 1.2171x; 1.2171x over previous
//
#include <hip/hip_runtime.h>
#include <math.h>

#define DIM 64
#define HEADS 4
#define BB 8
#define QQ 128
#define VV 128
#define NN (BB*QQ)   // 1024

// DPP quad_perm(1,0,3,2): swap adjacent lanes (xor 1) as a VALU op — no DS.
__device__ __forceinline__ float dpp_swap1(float x) {
    return __int_as_float(__builtin_amdgcn_update_dpp(
        0, __float_as_int(x), 0xB1 /*quad_perm 1,0,3,2*/, 0xF, 0xF, true));
}

// K1: Av[h][b*128+v][j] = (re,im) of sum_i values[b,v,i] * U[h, 64+i, j]
__global__ __launch_bounds__(256) void k_av(const float* __restrict__ values,
                                            const float* __restrict__ U_re,
                                            const float* __restrict__ U_im,
                                            float2* __restrict__ Av) {
    int tid = blockIdx.x * blockDim.x + threadIdx.x;
    int w = tid >> 6;          // 0..4095  (h, b*128+v)
    int j = tid & 63;
    int h = w >> 10;
    int rem = w & 1023;        // b*128 + v
    float vself = values[rem * DIM + j];
    const float* ur = U_re + (h * 2 * DIM + DIM) * DIM + j;   // bottom half of U
    const float* ui = U_im + (h * 2 * DIM + DIM) * DIM + j;
    float ar = 0.f, ai = 0.f;
    #pragma unroll
    for (int i = 0; i < DIM; ++i) {          // full unroll -> v_readlane
        float vi = __shfl(vself, i, 64);
        ar = fmaf(vi, ur[i * DIM], ar);
        ai = fmaf(vi, ui[i * DIM], ai);
    }
    Av[(h * 1024 + rem) * DIM + j] = make_float2(ar, ai);
}

// K2: block = n (1024 blocks), wave = head (4 waves), lane j = state dim.
// 128-step EUNN scan fused with the dense epilogue.
__global__ __launch_bounds__(256) void k_rnn_dense(
        const float* __restrict__ queries,
        const float* __restrict__ U_re,
        const float* __restrict__ U_im,
        const float* __restrict__ bias,
        const float* __restrict__ theta1,
        const float* __restrict__ phi1,
        const float* __restrict__ theta2,
        const float* __restrict__ phi2,
        const float* __restrict__ omega,
        const float2* __restrict__ Av,
        const float* __restrict__ W_dense,
        const float* __restrict__ b_dense,
        float* __restrict__ y) {
    int n = blockIdx.x;        // 0..1023
    int t = threadIdx.x;
    int h = t >> 6;            // head = wave
    int j = t & 63;            // state dim = lane
    int b = n >> 7;

    // ---- layer-1 coefficients: out = A1*self + B1*partner(xor 1) ----
    int k1 = j >> 1;
    float th1 = theta1[h * 32 + k1], ph1 = phi1[h * 32 + k1];
    float c1 = cosf(th1), s1 = sinf(th1);
    float A1r, A1i, B1r, B1i;
    if ((j & 1) == 0) {        // 'a': e1*(c1*a - s1*b)
        float er = cosf(ph1), ei = sinf(ph1);
        A1r = er * c1; A1i = ei * c1;
        B1r = -er * s1; B1i = -ei * s1;
    } else {                   // 'b': s1*a + c1*b
        A1r = c1; A1i = 0.f;
        B1r = s1; B1i = 0.f;
    }

    // ---- layer-2 coefficients (+omega folded): out = A2*self + B2*partner ----
    float A2r, A2i, B2r, B2i;
    int p2lane;
    if (j == 0 || j == 63) {
        A2r = 1.f; A2i = 0.f; B2r = 0.f; B2i = 0.f; p2lane = j;
    } else {
        int k2 = (j - 1) >> 1;
        float th2 = theta2[h * 31 + k2], ph2 = phi2[h * 31 + k2];
        float c2 = cosf(th2), s2 = sinf(th2);
        if (j & 1) {           // odd = 'a': e2*(c2*a - s2*b)
            float er = cosf(ph2), ei = sinf(ph2);
            A2r = er * c2; A2i = ei * c2;
            B2r = -er * s2; B2i = -ei * s2;
            p2lane = j + 1;
        } else {               // even = 'b': s2*a + c2*b
            A2r = c2; A2i = 0.f;
            B2r = s2; B2i = 0.f;
            p2lane = j - 1;
        }
    }
    {   // fold exp(i*omega)
        float om = omega[h * 64 + j];
        float eor = cosf(om), eoi = sinf(om);
        float tr, ti;
        tr = A2r * eor - A2i * eoi; ti = A2r * eoi + A2i * eor; A2r = tr; A2i = ti;
        tr = B2r * eor - B2i * eoi; ti = B2r * eoi + B2i * eor; B2r = tr; B2i = ti;
    }

    float bj = bias[h * 64 + j];

    // ---- Aq[h,n,j] = sum_i q[n,i] * U_top[h,i,j] ----
    float qself = queries[n * DIM + j];
    const float* ur = U_re + (h * 2 * DIM) * DIM + j;
    const float* ui = U_im + (h * 2 * DIM) * DIM + j;
    float uqr = 0.f, uqi = 0.f;
    #pragma unroll
    for (int i = 0; i < DIM; ++i) {          // full unroll -> v_readlane
        float qi = __shfl(qself, i, 64);
        uqr = fmaf(qi, ur[i * DIM], uqr);
        uqi = fmaf(qi, ui[i * DIM], uqi);
    }

    const float2* Avp = Av + (h * 8 + b) * VV * DIM + j;

    float hr = 0.f, hi = 0.f;
    #pragma unroll 4
    for (int v = 0; v < VV; ++v) {
        float2 av = Avp[v * DIM];
        // layer 1: partner via DPP (VALU, no DS)
        float pr = dpp_swap1(hr);
        float pi = dpp_swap1(hi);
        float t_r = A1r * hr - A1i * hi + B1r * pr - B1i * pi;
        float t_i = A1r * hi + A1i * hr + B1r * pi + B1i * pr;
        // layer 2 (+ omega): partner via bpermute
        float qr  = __shfl(t_r, p2lane, 64);
        float qi2 = __shfl(t_i, p2lane, 64);
        float s_r = A2r * t_r - A2i * t_i + B2r * qr - B2i * qi2;
        float s_i = A2r * t_i + A2i * t_r + B2r * qi2 + B2i * qr;
        // input u = Aq + Av[v]
        float zr = s_r + uqr + av.x;
        float zi = s_i + uqi + av.y;
        // fast modrelu: z * relu(|z|+b) / (|z|+1e-5), via v_rsq + v_rcp
        float q2 = fmaf(zr, zr, fmaf(zi, zi, 1e-30f));
        float rs = __builtin_amdgcn_rsqf(q2);
        float m = q2 * rs;                       // = sqrt(q2)
        float tpos = fmaxf(m + bj, 0.f);
        float inv = __builtin_amdgcn_rcpf(m + 1e-5f);
        float sc = tpos * inv;
        hr = zr * sc;
        hi = zi * sc;
    }

    // ---- fused dense: y[n,:] = b_dense + acc_row @ W ----
    __shared__ float s_acc[HEADS * DIM];     // 256
    __shared__ float s_part[256];
    s_acc[h * 64 + j] = hr;                  // Re(hT)
    __syncthreads();

    int qq = t >> 6;                          // quarter of the k range
    int jj = t & 63;                          // output column
    const float* Wp = W_dense + (qq * 64) * DIM + jj;
    float part = 0.f;
    #pragma unroll 8
    for (int k = 0; k < 64; ++k)
        part = fmaf(s_acc[qq * 64 + k], Wp[k * DIM], part);  // s_acc broadcast, W coalesced
    s_part[t] = part;
    __syncthreads();
    if (t < 64) {
        float s = b_dense[jj] + s_part[jj] + s_part[64 + jj]
                + s_part[128 + jj] + s_part[192 + jj];
        y[n * DIM + jj] = s;
    }
}

extern "C" void kernel_launch(void* const* d_in, const int* in_sizes, int n_in,
                              void* d_out, int out_size, void* d_ws, size_t ws_size,
                              hipStream_t stream) {
    const float* queries = (const float*)d_in[0];
    const float* values  = (const float*)d_in[1];
    const float* U_re    = (const float*)d_in[2];
    const float* U_im    = (const float*)d_in[3];
    const float* bias    = (const float*)d_in[4];
    const float* theta1  = (const float*)d_in[5];
    const float* phi1    = (const float*)d_in[6];
    const float* theta2  = (const float*)d_in[7];
    const float* phi2    = (const float*)d_in[8];
    const float* omega   = (const float*)d_in[9];
    const float* W_dense = (const float*)d_in[10];
    const float* b_dense = (const float*)d_in[11];
    float* y = (float*)d_out;

    float2* Av = (float2*)d_ws;   // HEADS*BB*VV*DIM float2 = 2 MB

    k_av<<<1024, 256, 0, stream>>>(values, U_re, U_im, Av);
    k_rnn_dense<<<1024, 256, 0, stream>>>(queries, U_re, U_im, bias, theta1,
                                          phi1, theta2, phi2, omega, Av,
                                          W_dense, b_dense, y);
}